// Round 9
// baseline (450.074 us; speedup 1.0000x reference)
//
#include <hip/hip_runtime.h>
#include <math.h>

#define SQ 4096
#define DM 1024
#define NB 4
#define MT (NB*SQ)   // 16384 flattened rows
#define XN ((size_t)MT*DM)
#define NCVT 19456   // (XN + 3*DM*DM)/1024 convert blocks in cvt_all
#define NTILES 528   // causal 128x128 tiles per batch (packed S)
#define STILE 16384  // elems per packed S tile (128*128)

typedef __attribute__((ext_vector_type(4))) float f32x4;
typedef __attribute__((ext_vector_type(8))) short s16x8;

// pv balanced bins: 12 bins per (batch, nt64), each EXACTLY 44 K-units
// (K-unit = one 128-k-tile; item mt has mt+1 units; items 1..32 partition:
// 10 pairs {31,11}..{22,20}, then {21,10,9,0}, then {8..1}).
__device__ const int PV_BIN_START[13] = {0,2,4,6,8,10,12,14,16,18,20,24,32};
__device__ const int PV_BIN_MT[32] = {31,11, 30,12, 29,13, 28,14, 27,15, 26,16,
                                      25,17, 24,18, 23,19, 22,20, 21,10,9,0,
                                      8,7,6,5,4,3,2,1};

__device__ __forceinline__ unsigned short f2bf(float f) {
  union { float f; unsigned int u; } v; v.f = f;
  unsigned int u = v.u;
  u += 0x7fffu + ((u >> 16) & 1u);   // RNE
  return (unsigned short)(u >> 16);
}

__device__ __forceinline__ float bf2f(unsigned short u) {
  union { unsigned int i; float f; } v; v.i = ((unsigned int)u) << 16;
  return v.f;
}

__device__ __forceinline__ void async16(const void* g, void* l) {
  __builtin_amdgcn_global_load_lds(
      (const __attribute__((address_space(1))) unsigned int*)g,
      (__attribute__((address_space(3))) unsigned int*)l, 16, 0, 0);
}

// ---------------- fp32 -> bf16 convert (all 4 inputs) + zero row-sum accumulator ----
__global__ __launch_bounds__(256)
void cvt_all(const float* __restrict__ x, const float* __restrict__ Wq,
             const float* __restrict__ Wk, const float* __restrict__ Wv,
             unsigned short* __restrict__ xb, unsigned short* __restrict__ Wb,
             float* __restrict__ l) {
  if (blockIdx.x >= NCVT) {
    int r = (blockIdx.x - NCVT) * 256 + threadIdx.x;
    l[r] = 0.f;
    return;
  }
  size_t i = ((size_t)blockIdx.x * 256 + threadIdx.x) * 4;
  const float* src; unsigned short* dst;
  if (i < XN) { src = x + i; dst = xb + i; }
  else {
    size_t r = i - XN;
    int w = (int)(r >> 20);                 // DM*DM == 2^20
    size_t off = r & (((size_t)1 << 20) - 1);
    src = (w == 0 ? Wq : (w == 1 ? Wk : Wv)) + off;
    dst = Wb + r;
  }
  float4 f = *(const float4*)src;
  ushort4 o;
  o.x = f2bf(f.x); o.y = f2bf(f.y); o.z = f2bf(f.z); o.w = f2bf(f.w);
  *(ushort4*)dst = o;
}

// ---------------- shared m97-style 128x128xBK64 K-loop, hoisted addressing ----------------
// NOTE (r0-r3): 8-phase / 256^2 variants tried three times (132.5 / 127.0 / 153.5 us)
// — all regress or tie vs this 128^2 3-blocks/CU body. The 2-phase structure's 35%
// MfmaUtil comes from cross-BLOCK overlap (3/CU); geometry that drops blocks/CU loses
// it (r6: 256^2 -> 19%). k-step is ~95% stall / ~5% MFMA: TLP is everything.
template<int LDA, int LDB>
__device__ __forceinline__ void gemm_tile_body(
    const unsigned short* __restrict__ A, const unsigned short* __restrict__ B,
    unsigned short* As, unsigned short* Bs,
    int m0, int n0, int kext, f32x4 acc[4][4]) {
  const int tid = threadIdx.x, lane = tid & 63, wid = tid >> 6;
  const int quad = lane >> 4, l15 = lane & 15;
  const int wm = wid & 1, wn = wid >> 1;

  const int rbase = wid * 32 + (lane >> 3);
  const int kg8   = ((lane & 7) ^ (lane >> 3)) * 8;
  const unsigned short* Ab = A + (size_t)(m0 + rbase) * LDA + kg8;
  const unsigned short* Bb = B + (size_t)(n0 + rbase) * LDB + kg8;
  unsigned short* Asl = As + (wid * 256 + lane) * 8;
  unsigned short* Bsl = Bs + (wid * 256 + lane) * 8;
  const int xorq = (quad ^ (l15 & 7)) * 8;
  const int am = (wm * 64 + l15) * 64 + xorq;
  const int bn = (wn * 64 + l15) * 64 + xorq;

  for (int k0 = 0; k0 < kext; k0 += 64) {
#pragma unroll
    for (int c = 0; c < 4; c++) {
      async16(Ab + (size_t)c * 8 * LDA + k0, Asl + c * 512);
      async16(Bb + (size_t)c * 8 * LDB + k0, Bsl + c * 512);
    }
    asm volatile("s_waitcnt vmcnt(0)" ::: "memory");
    __syncthreads();
#pragma unroll
    for (int ks = 0; ks < 2; ks++) {
      const int ax = am ^ (ks * 32), bx = bn ^ (ks * 32);
      s16x8 af[4], bfr[4];
#pragma unroll
      for (int t = 0; t < 4; t++) {
        af[t]  = *(const s16x8*)(As + ax + t * 1024);
        bfr[t] = *(const s16x8*)(Bs + bx + t * 1024);
      }
#pragma unroll
      for (int tm = 0; tm < 4; tm++)
#pragma unroll
        for (int tn = 0; tn < 4; tn++)
          acc[tm][tn] = __builtin_amdgcn_mfma_f32_16x16x32_bf16(af[tm], bfr[tn], acc[tm][tn], 0, 0, 0);
    }
    __syncthreads();
  }
}

// ---------------- QKV projection, single dispatch: Q,K (rope) + V (direct-Vt) ----------
// grid (128, 24): by>>3 = mat; n0 = (by&7)*128. x-fastest: consecutive blocks share
// the W slab (L2-resident -> proj runs at the structural ceiling). Do NOT swizzle this
// grid (earlier %8 swizzle regressed FETCH 136->323 MB).
__global__ __launch_bounds__(256, 3)
void proj_all(const unsigned short* __restrict__ A,
              const unsigned short* __restrict__ Wb,
              unsigned short* __restrict__ QKV) {
  __shared__ unsigned short As[128 * 64];
  __shared__ unsigned short Bs[128 * 64];
  const int lane = threadIdx.x & 63, wid = threadIdx.x >> 6;
  const int quad = lane >> 4, l15 = lane & 15;
  const int wm = wid & 1, wn = wid >> 1;
  const int mat = blockIdx.y >> 3;                 // 0,1 -> rope; 2 -> V
  const int m0 = blockIdx.x * 128, n0 = (blockIdx.y & 7) * 128;

  f32x4 zero = {0.f, 0.f, 0.f, 0.f};
  f32x4 acc[4][4];
#pragma unroll
  for (int i = 0; i < 4; i++)
#pragma unroll
    for (int j = 0; j < 4; j++) acc[i][j] = zero;

  gemm_tile_body<DM, DM>(A, Wb + (size_t)mat * DM * DM, As, Bs, m0, n0, DM, acc);

  if (mat < 2) {
    unsigned short* C = QKV + (size_t)mat * XN;
    const bool ev = (lane & 1) == 0;
#pragma unroll
    for (int tm = 0; tm < 4; tm++) {
      int rowb = m0 + wm * 64 + tm * 16 + quad * 4;
#pragma unroll
      for (int tn = 0; tn < 4; tn++) {
        int col = n0 + wn * 64 + tn * 16 + l15;
        f32x4 v = acc[tm][tn];
        float invr = exp2f(-(float)(col & ~1) * (13.287712379549449f / 1024.0f)) * 0.15915494309f;
#pragma unroll
        for (int g = 0; g < 4; g++) {
          int row = rowb + g;
          float rev = (float)(row & (SQ - 1)) * invr;
          rev -= floorf(rev);
          float sn, cs;
          __sincosf(rev * 6.283185307179586f, &sn, &cs);
          float part = __shfl_xor(v[g], 1);
          float e = ev ? v[g] : part;
          float o = ev ? part : v[g];
          float re = e * cs - o * sn;
          float ro = e * sn + o * cs;
          if (ev) {
            unsigned int pk = (unsigned int)f2bf(re) | ((unsigned int)f2bf(ro) << 16);
            *(unsigned int*)(C + (size_t)row * DM + col) = pk;
          }
        }
      }
    }
  } else {
    unsigned short* Vt = QKV + (size_t)2 * XN;     // [b][d][s]
#pragma unroll
    for (int tm = 0; tm < 4; tm++) {
      int rowb = m0 + wm * 64 + tm * 16 + quad * 4;
      int b = rowb >> 12;
      int s = rowb & (SQ - 1);                     // 4 rows, same batch, s..s+3
#pragma unroll
      for (int tn = 0; tn < 4; tn++) {
        int col = n0 + wn * 64 + tn * 16 + l15;
        f32x4 v = acc[tm][tn];
        ushort4 o;
        o.x = f2bf(v[0]); o.y = f2bf(v[1]); o.z = f2bf(v[2]); o.w = f2bf(v[3]);
        *(ushort4*)(Vt + (size_t)b * DM * SQ + (size_t)col * SQ + s) = o;
      }
    }
  }
}

// ---------------- pass1: P' = exp(QK^T/32), causal, PACKED-tile bf16 out ----------
// 2112 blocks, XCD-chunked swizzle (2112 = 8 x 264, bijective): XCD x gets the
// contiguous triangular-id chunk [264x, 264x+264) -> Q row-slabs + lockstep K march
// L2-amplified (r7: part of the -34 us step).
__global__ __launch_bounds__(256, 3)
void qk_gemm(const unsigned short* __restrict__ Q, const unsigned short* __restrict__ K,
             unsigned short* __restrict__ S, float* __restrict__ l) {
  __shared__ unsigned short As[128 * 64];
  __shared__ unsigned short Bs[128 * 64];
  const int lane = threadIdx.x & 63, wid = threadIdx.x >> 6;
  const int quad = lane >> 4, l15 = lane & 15;
  const int wm = wid & 1, wn = wid >> 1;

  const int logical = (blockIdx.x & 7) * 264 + (blockIdx.x >> 3);
  const int b = logical / NTILES;
  int t = logical - b * NTILES;
  int mt = (int)((sqrtf(8.f * (float)t + 1.f) - 1.f) * 0.5f);
  while ((mt + 1) * (mt + 2) / 2 <= t) ++mt;
  while (mt * (mt + 1) / 2 > t) --mt;
  int nt = t - mt * (mt + 1) / 2;

  const unsigned short* Qg = Q + (size_t)b * SQ * DM;
  const unsigned short* Kg = K + (size_t)b * SQ * DM;
  unsigned short* Sg = S + (size_t)b * NTILES * STILE + ((size_t)t << 14);
  float* lrow = l + b * SQ;

  f32x4 zero = {0.f, 0.f, 0.f, 0.f};
  f32x4 acc[4][4];
#pragma unroll
  for (int i = 0; i < 4; i++)
#pragma unroll
    for (int j = 0; j < 4; j++) acc[i][j] = zero;

  gemm_tile_body<DM, DM>(Qg, Kg, As, Bs, mt * 128, nt * 128, DM, acc);

  const bool ev = (lane & 1) == 0;
#pragma unroll
  for (int tm = 0; tm < 4; tm++) {
    int lr = wm * 64 + tm * 16 + quad * 4;          // tile-local row
    int grow = mt * 128 + lr;
    float rsum[4] = {0.f, 0.f, 0.f, 0.f};
#pragma unroll
    for (int tn = 0; tn < 4; tn++) {
      int lc = wn * 64 + tn * 16 + l15;             // tile-local col
      int gcol = nt * 128 + lc;
      f32x4 v = acc[tm][tn];
#pragma unroll
      for (int g = 0; g < 4; g++) {
        float p = (gcol <= grow + g) ? __expf(v[g] * 0.03125f) : 0.f;
        rsum[g] += p;
        float part = __shfl_xor(p, 1);
        if (ev) {
          unsigned int pk = (unsigned int)f2bf(p) | ((unsigned int)f2bf(part) << 16);
          *(unsigned int*)(Sg + (size_t)(lr + g) * 128 + lc) = pk;
        }
      }
    }
#pragma unroll
    for (int g = 0; g < 4; g++) {
      float s = rsum[g];
#pragma unroll
      for (int o = 8; o >= 1; o >>= 1) s += __shfl_xor(s, o);
      if (l15 == 0) atomicAdd(&lrow[grow + g], s);
    }
  }
}

// ---------------- pass2: O = (P' @ V)/l, 128m x 64n, 12 balanced bins, 3 blocks/CU ----
// 768 blocks (= 3/CU exactly, 12 waves/CU like proj/qk): logical = (b*12+qb)*16+nt.
// Bin qb covers m-tiles PV_BIN_MT[start..end) totalling exactly 44 K-units -> all
// blocks uniform (88 BK64 steps), zero tail. LDS 24 KB (A 128x64 + B 64x64).
// XCD swizzle (768 = 8 x 96): each XCD gets 6 bins x all 16 nt of one batch -> the
// 16 nt-blocks of a bin read the SAME packed-P tile at the same j (P staging
// L2-deduped x16; P is the dominant stream at n=64).
// n64 B algebra = r4's gemm_n64_body (HW-verified in the r4 passing run).
__global__ __launch_bounds__(256, 3)
void pv_bins(const unsigned short* __restrict__ P, const unsigned short* __restrict__ Vt,
             const float* __restrict__ l, float* __restrict__ O) {
  __shared__ unsigned short As[128 * 64];
  __shared__ unsigned short Bs[64 * 64];
  const int lane = threadIdx.x & 63, wid = threadIdx.x >> 6;
  const int quad = lane >> 4, l15 = lane & 15;
  const int wm = wid & 1, wn = wid >> 1;           // wn in {0,1}: 32-col halves

  const int logical = (blockIdx.x & 7) * 96 + (blockIdx.x >> 3);
  const int nt = logical & 15;
  const int qb = (logical >> 4) % 12;
  const int b  = logical / 192;

  const unsigned short* Pg = P + (size_t)b * NTILES * STILE;
  const unsigned short* Vg = Vt + (size_t)b * DM * SQ;
  const float* lg = l + b * SQ;
  float* Og = O + (size_t)b * SQ * DM;
  const int n0 = nt * 64;

  const int rbase  = wid * 32 + (lane >> 3);       // A rows 0..127 (+8c)
  const int rbaseB = wid * 16 + (lane >> 3);       // B rows 0..63 (+8c)
  const int kg8 = ((lane & 7) ^ (lane >> 3)) * 8;
  const unsigned short* Bb = Vg + (size_t)(n0 + rbaseB) * SQ + kg8;
  unsigned short* Asl = As + (wid * 256 + lane) * 8;
  unsigned short* Bsl = Bs + (wid * 128 + lane) * 8;
  const int xorq = (quad ^ (l15 & 7)) * 8;
  const int am = (wm * 64 + l15) * 64 + xorq;
  const int bn = (wn * 32 + l15) * 64 + xorq;
  const bool ev = (lane & 1) == 0;

  f32x4 zero = {0.f, 0.f, 0.f, 0.f};
  const int i0 = PV_BIN_START[qb], i1 = PV_BIN_START[qb + 1];
#pragma unroll 1
  for (int idx = i0; idx < i1; ++idx) {
    const int mt = PV_BIN_MT[idx];
    const int tb = mt * (mt + 1) / 2;              // packed tri base of row mt
    f32x4 acc[4][2];
#pragma unroll
    for (int i = 0; i < 4; i++) { acc[i][0] = zero; acc[i][1] = zero; }

    for (int j = 0; j <= mt; ++j) {
      const unsigned short* At = Pg + ((size_t)(tb + j) << 14) + kg8;
      const int kbase = j * 128;
#pragma unroll 1
      for (int ks2 = 0; ks2 < 2; ks2++) {
        const int ko = ks2 * 64;
#pragma unroll
        for (int c = 0; c < 4; c++)
          async16(At + (size_t)(rbase + 8 * c) * 128 + ko, Asl + c * 512);
#pragma unroll
        for (int c = 0; c < 2; c++)
          async16(Bb + (size_t)c * 8 * SQ + kbase + ko, Bsl + c * 512);
        asm volatile("s_waitcnt vmcnt(0)" ::: "memory");
        __syncthreads();
#pragma unroll
        for (int ks = 0; ks < 2; ks++) {
          const int ax = am ^ (ks * 32), bx = bn ^ (ks * 32);
          s16x8 af[4], bfr[2];
#pragma unroll
          for (int u = 0; u < 4; u++) af[u] = *(const s16x8*)(As + ax + u * 1024);
#pragma unroll
          for (int u = 0; u < 2; u++) bfr[u] = *(const s16x8*)(Bs + bx + u * 1024);
#pragma unroll
          for (int tm = 0; tm < 4; tm++)
#pragma unroll
            for (int tn = 0; tn < 2; tn++)
              acc[tm][tn] = __builtin_amdgcn_mfma_f32_16x16x32_bf16(af[tm], bfr[tn], acc[tm][tn], 0, 0, 0);
        }
        __syncthreads();
      }
    }

#pragma unroll
    for (int tm = 0; tm < 4; tm++) {
      int grow = mt * 128 + wm * 64 + tm * 16 + quad * 4;
      float rl[4];
#pragma unroll
      for (int g = 0; g < 4; g++) rl[g] = 1.0f / lg[grow + g];
#pragma unroll
      for (int tn = 0; tn < 2; tn++) {
        int col = n0 + wn * 32 + tn * 16 + l15;
        f32x4 v = acc[tm][tn];
#pragma unroll
        for (int g = 0; g < 4; g++) {
          float val = v[g] * rl[g];
          float part = __shfl_xor(val, 1);
          if (ev) {
            float2 st; st.x = val; st.y = part;
            *(float2*)(Og + (size_t)(grow + g) * DM + col) = st;
          }
        }
      }
    }
  }
}

extern "C" void kernel_launch(void* const* d_in, const int* in_sizes, int n_in,
                              void* d_out, int out_size, void* d_ws, size_t ws_size,
                              hipStream_t stream) {
  const float* x  = (const float*)d_in[0];
  const float* Wq = (const float*)d_in[1];
  const float* Wk = (const float*)d_in[2];
  const float* Wv = (const float*)d_in[3];
  float* out = (float*)d_out;

  // workspace layout (bf16 elems). QKV first; packed S (69.2 MB) overlays the
  // dead-after-proj xb+Wb region. Peak 169.9 MB <= proven ws floor (174.1 MB).
  unsigned short* Qb  = (unsigned short*)d_ws;
  unsigned short* xb  = Qb + 3 * XN;
  unsigned short* Wb  = xb + XN;
  unsigned short* Sb  = xb;                              // overlay
  float* lfull = (float*)(Sb + (size_t)NB * NTILES * STILE);

  (void)ws_size; (void)in_sizes; (void)n_in; (void)out_size;

  cvt_all<<<NCVT + 64, 256, 0, stream>>>(x, Wq, Wk, Wv, xb, Wb, lfull);

  proj_all<<<dim3(MT / 128, 24), 256, 0, stream>>>(xb, Wb, Qb);

  qk_gemm<<<NB * NTILES, 256, 0, stream>>>(Qb, Qb + XN, Sb, lfull);

  pv_bins<<<768, 256, 0, stream>>>(Sb, Qb + 2 * XN, lfull, out);
}

// Round 10
// 420.259 us; speedup vs baseline: 1.0709x; 1.0709x over previous
//
#include <hip/hip_runtime.h>
#include <math.h>

#define SQ 4096
#define DM 1024
#define NB 4
#define MT (NB*SQ)   // 16384 flattened rows
#define XN ((size_t)MT*DM)
#define NCVT 19456   // (XN + 3*DM*DM)/1024 convert blocks in cvt_all
#define NTILES 528   // causal 128x128 tiles per batch (packed S)
#define STILE 16384  // elems per packed S tile (128*128)

typedef __attribute__((ext_vector_type(4))) float f32x4;
typedef __attribute__((ext_vector_type(8))) short s16x8;

__device__ __forceinline__ unsigned short f2bf(float f) {
  union { float f; unsigned int u; } v; v.f = f;
  unsigned int u = v.u;
  u += 0x7fffu + ((u >> 16) & 1u);   // RNE
  return (unsigned short)(u >> 16);
}

__device__ __forceinline__ float bf2f(unsigned short u) {
  union { unsigned int i; float f; } v; v.i = ((unsigned int)u) << 16;
  return v.f;
}

__device__ __forceinline__ void async16(const void* g, void* l) {
  __builtin_amdgcn_global_load_lds(
      (const __attribute__((address_space(1))) unsigned int*)g,
      (__attribute__((address_space(3))) unsigned int*)l, 16, 0, 0);
}

// ---------------- fp32 -> bf16 convert (all 4 inputs) + zero row-sum accumulator ----
__global__ __launch_bounds__(256)
void cvt_all(const float* __restrict__ x, const float* __restrict__ Wq,
             const float* __restrict__ Wk, const float* __restrict__ Wv,
             unsigned short* __restrict__ xb, unsigned short* __restrict__ Wb,
             float* __restrict__ l) {
  if (blockIdx.x >= NCVT) {
    int r = (blockIdx.x - NCVT) * 256 + threadIdx.x;
    l[r] = 0.f;
    return;
  }
  size_t i = ((size_t)blockIdx.x * 256 + threadIdx.x) * 4;
  const float* src; unsigned short* dst;
  if (i < XN) { src = x + i; dst = xb + i; }
  else {
    size_t r = i - XN;
    int w = (int)(r >> 20);                 // DM*DM == 2^20
    size_t off = r & (((size_t)1 << 20) - 1);
    src = (w == 0 ? Wq : (w == 1 ? Wk : Wv)) + off;
    dst = Wb + r;
  }
  float4 f = *(const float4*)src;
  ushort4 o;
  o.x = f2bf(f.x); o.y = f2bf(f.y); o.z = f2bf(f.z); o.w = f2bf(f.w);
  *(ushort4*)dst = o;
}

// ---------------- shared m97-style 128x128xBK64 K-loop, hoisted addressing ----------------
// NOTE (r0-r8 ledger): 8-phase / 256^2 variants (132.5/127.0/153.5 us) all lose to
// this 128^2 body; pv at n=64 3-blocks/CU (r8: +33 us) loses to n=128 2-blocks/CU.
// The structure wants MAX blocks/CU at MIN issued-bytes; stalls are per-issued-byte.
template<int LDA, int LDB>
__device__ __forceinline__ void gemm_tile_body(
    const unsigned short* __restrict__ A, const unsigned short* __restrict__ B,
    unsigned short* As, unsigned short* Bs,
    int m0, int n0, int kext, f32x4 acc[4][4]) {
  const int tid = threadIdx.x, lane = tid & 63, wid = tid >> 6;
  const int quad = lane >> 4, l15 = lane & 15;
  const int wm = wid & 1, wn = wid >> 1;

  const int rbase = wid * 32 + (lane >> 3);
  const int kg8   = ((lane & 7) ^ (lane >> 3)) * 8;
  const unsigned short* Ab = A + (size_t)(m0 + rbase) * LDA + kg8;
  const unsigned short* Bb = B + (size_t)(n0 + rbase) * LDB + kg8;
  unsigned short* Asl = As + (wid * 256 + lane) * 8;
  unsigned short* Bsl = Bs + (wid * 256 + lane) * 8;
  const int xorq = (quad ^ (l15 & 7)) * 8;
  const int am = (wm * 64 + l15) * 64 + xorq;
  const int bn = (wn * 64 + l15) * 64 + xorq;

  for (int k0 = 0; k0 < kext; k0 += 64) {
#pragma unroll
    for (int c = 0; c < 4; c++) {
      async16(Ab + (size_t)c * 8 * LDA + k0, Asl + c * 512);
      async16(Bb + (size_t)c * 8 * LDB + k0, Bsl + c * 512);
    }
    asm volatile("s_waitcnt vmcnt(0)" ::: "memory");
    __syncthreads();
#pragma unroll
    for (int ks = 0; ks < 2; ks++) {
      const int ax = am ^ (ks * 32), bx = bn ^ (ks * 32);
      s16x8 af[4], bfr[4];
#pragma unroll
      for (int t = 0; t < 4; t++) {
        af[t]  = *(const s16x8*)(As + ax + t * 1024);
        bfr[t] = *(const s16x8*)(Bs + bx + t * 1024);
      }
#pragma unroll
      for (int tm = 0; tm < 4; tm++)
#pragma unroll
        for (int tn = 0; tn < 4; tn++)
          acc[tm][tn] = __builtin_amdgcn_mfma_f32_16x16x32_bf16(af[tm], bfr[tn], acc[tm][tn], 0, 0, 0);
    }
    __syncthreads();
  }
}

// ---------------- QKV projection, single dispatch: Q,K (rope) + V (direct-Vt) ----------
// grid (128, 24): by>>3 = mat; n0 = (by&7)*128. x-fastest: consecutive blocks share
// the W slab (L2-resident). Do NOT swizzle this grid (regressed FETCH 136->323 MB).
__global__ __launch_bounds__(256, 3)
void proj_all(const unsigned short* __restrict__ A,
              const unsigned short* __restrict__ Wb,
              unsigned short* __restrict__ QKV) {
  __shared__ unsigned short As[128 * 64];
  __shared__ unsigned short Bs[128 * 64];
  const int lane = threadIdx.x & 63, wid = threadIdx.x >> 6;
  const int quad = lane >> 4, l15 = lane & 15;
  const int wm = wid & 1, wn = wid >> 1;
  const int mat = blockIdx.y >> 3;                 // 0,1 -> rope; 2 -> V
  const int m0 = blockIdx.x * 128, n0 = (blockIdx.y & 7) * 128;

  f32x4 zero = {0.f, 0.f, 0.f, 0.f};
  f32x4 acc[4][4];
#pragma unroll
  for (int i = 0; i < 4; i++)
#pragma unroll
    for (int j = 0; j < 4; j++) acc[i][j] = zero;

  gemm_tile_body<DM, DM>(A, Wb + (size_t)mat * DM * DM, As, Bs, m0, n0, DM, acc);

  if (mat < 2) {
    unsigned short* C = QKV + (size_t)mat * XN;
    const bool ev = (lane & 1) == 0;
#pragma unroll
    for (int tm = 0; tm < 4; tm++) {
      int rowb = m0 + wm * 64 + tm * 16 + quad * 4;
#pragma unroll
      for (int tn = 0; tn < 4; tn++) {
        int col = n0 + wn * 64 + tn * 16 + l15;
        f32x4 v = acc[tm][tn];
        float invr = exp2f(-(float)(col & ~1) * (13.287712379549449f / 1024.0f)) * 0.15915494309f;
#pragma unroll
        for (int g = 0; g < 4; g++) {
          int row = rowb + g;
          float rev = (float)(row & (SQ - 1)) * invr;
          rev -= floorf(rev);
          float sn, cs;
          __sincosf(rev * 6.283185307179586f, &sn, &cs);
          float part = __shfl_xor(v[g], 1);
          float e = ev ? v[g] : part;
          float o = ev ? part : v[g];
          float re = e * cs - o * sn;
          float ro = e * sn + o * cs;
          if (ev) {
            unsigned int pk = (unsigned int)f2bf(re) | ((unsigned int)f2bf(ro) << 16);
            *(unsigned int*)(C + (size_t)row * DM + col) = pk;
          }
        }
      }
    }
  } else {
    unsigned short* Vt = QKV + (size_t)2 * XN;     // [b][d][s]
#pragma unroll
    for (int tm = 0; tm < 4; tm++) {
      int rowb = m0 + wm * 64 + tm * 16 + quad * 4;
      int b = rowb >> 12;
      int s = rowb & (SQ - 1);                     // 4 rows, same batch, s..s+3
#pragma unroll
      for (int tn = 0; tn < 4; tn++) {
        int col = n0 + wn * 64 + tn * 16 + l15;
        f32x4 v = acc[tm][tn];
        ushort4 o;
        o.x = f2bf(v[0]); o.y = f2bf(v[1]); o.z = f2bf(v[2]); o.w = f2bf(v[3]);
        *(ushort4*)(Vt + (size_t)b * DM * SQ + (size_t)col * SQ + s) = o;
      }
    }
  }
}

// ---------------- pass1: P' = exp(QK^T/32), causal, PACKED-tile bf16 out ----------
// 2112 blocks, XCD-chunked swizzle (2112 = 8 x 264, bijective): XCD x gets the
// contiguous triangular-id chunk [264x, 264x+264) -> Q row-slabs + lockstep K march
// L2-amplified (r7: part of the -34 us step).
__global__ __launch_bounds__(256, 3)
void qk_gemm(const unsigned short* __restrict__ Q, const unsigned short* __restrict__ K,
             unsigned short* __restrict__ S, float* __restrict__ l) {
  __shared__ unsigned short As[128 * 64];
  __shared__ unsigned short Bs[128 * 64];
  const int lane = threadIdx.x & 63, wid = threadIdx.x >> 6;
  const int quad = lane >> 4, l15 = lane & 15;
  const int wm = wid & 1, wn = wid >> 1;

  const int logical = (blockIdx.x & 7) * 264 + (blockIdx.x >> 3);
  const int b = logical / NTILES;
  int t = logical - b * NTILES;
  int mt = (int)((sqrtf(8.f * (float)t + 1.f) - 1.f) * 0.5f);
  while ((mt + 1) * (mt + 2) / 2 <= t) ++mt;
  while (mt * (mt + 1) / 2 > t) --mt;
  int nt = t - mt * (mt + 1) / 2;

  const unsigned short* Qg = Q + (size_t)b * SQ * DM;
  const unsigned short* Kg = K + (size_t)b * SQ * DM;
  unsigned short* Sg = S + (size_t)b * NTILES * STILE + ((size_t)t << 14);
  float* lrow = l + b * SQ;

  f32x4 zero = {0.f, 0.f, 0.f, 0.f};
  f32x4 acc[4][4];
#pragma unroll
  for (int i = 0; i < 4; i++)
#pragma unroll
    for (int j = 0; j < 4; j++) acc[i][j] = zero;

  gemm_tile_body<DM, DM>(Qg, Kg, As, Bs, mt * 128, nt * 128, DM, acc);

  const bool ev = (lane & 1) == 0;
#pragma unroll
  for (int tm = 0; tm < 4; tm++) {
    int lr = wm * 64 + tm * 16 + quad * 4;          // tile-local row
    int grow = mt * 128 + lr;
    float rsum[4] = {0.f, 0.f, 0.f, 0.f};
#pragma unroll
    for (int tn = 0; tn < 4; tn++) {
      int lc = wn * 64 + tn * 16 + l15;             // tile-local col
      int gcol = nt * 128 + lc;
      f32x4 v = acc[tm][tn];
#pragma unroll
      for (int g = 0; g < 4; g++) {
        float p = (gcol <= grow + g) ? __expf(v[g] * 0.03125f) : 0.f;
        rsum[g] += p;
        float part = __shfl_xor(p, 1);
        if (ev) {
          unsigned int pk = (unsigned int)f2bf(p) | ((unsigned int)f2bf(part) << 16);
          *(unsigned int*)(Sg + (size_t)(lr + g) * 128 + lc) = pk;
        }
      }
    }
#pragma unroll
    for (int g = 0; g < 4; g++) {
      float s = rsum[g];
#pragma unroll
      for (int o = 8; o >= 1; o >>= 1) s += __shfl_xor(s, o);
      if (l15 == 0) atomicAdd(&lrow[grow + g], s);
    }
  }
}

// ---------------- pass2: O = (P' @ V)/l, merged complementary pair, shared-V staging ----
// 512 blocks (2/CU), logical = ((b*16 + p)*8 + nt): block computes m-tiles mt=p AND
// mt=31-p at n-tile nt in ONE k-loop over j=0..(31-p): V tile j staged ONCE (both
// halves read the same V rows n0..n0+127 from k=0!), P tiles for both columns while
// j <= p. Issued bytes: V 135->100 MB/batch (-13% total) at identical balance
// (33 A-units + (32-p) V-units), barrier structure, and block mapping as r7's 417us
// pv_pair. XCD swizzle (512 = 8 x 64): nt-siblings share P tiles in L2.
__global__ __launch_bounds__(256, 2)
void pv_pair(const unsigned short* __restrict__ P, const unsigned short* __restrict__ Vt,
             const float* __restrict__ l, float* __restrict__ O) {
  __shared__ unsigned short As0[128 * 64];   // short column (mt = p)
  __shared__ unsigned short As1[128 * 64];   // long column (mt = 31-p)
  __shared__ unsigned short Bs[128 * 64];
  const int lane = threadIdx.x & 63, wid = threadIdx.x >> 6;
  const int quad = lane >> 4, l15 = lane & 15;
  const int wm = wid & 1, wn = wid >> 1;

  const int logical = (blockIdx.x & 7) * 64 + (blockIdx.x >> 3);
  const int b = logical >> 7;                      // 128 logical ids per batch
  const int p = (logical >> 3) & 15;
  const int nt = logical & 7;

  const unsigned short* Pg = P + (size_t)b * NTILES * STILE;
  const unsigned short* Vg = Vt + (size_t)b * DM * SQ;
  const float* lg = l + b * SQ;
  float* Og = O + (size_t)b * SQ * DM;
  const int n0 = nt * 128;

  const int mt_s = p, mt_l = 31 - p;
  const int tb_s = mt_s * (mt_s + 1) / 2;
  const int tb_l = mt_l * (mt_l + 1) / 2;
  const int js_max = p + 1, jl_max = 32 - p;

  const int rbase = wid * 32 + (lane >> 3);
  const int kg8 = ((lane & 7) ^ (lane >> 3)) * 8;
  const unsigned short* Bb = Vg + (size_t)(n0 + rbase) * SQ + kg8;
  unsigned short* Asl0 = As0 + (wid * 256 + lane) * 8;
  unsigned short* Asl1 = As1 + (wid * 256 + lane) * 8;
  unsigned short* Bsl  = Bs  + (wid * 256 + lane) * 8;
  const int xorq = (quad ^ (l15 & 7)) * 8;
  const int am = (wm * 64 + l15) * 64 + xorq;
  const int bn = (wn * 64 + l15) * 64 + xorq;
  const bool ev = (lane & 1) == 0;

  f32x4 zero = {0.f, 0.f, 0.f, 0.f};
  f32x4 acc_s[4][4], acc_l[4][4];
#pragma unroll
  for (int i = 0; i < 4; i++)
#pragma unroll
    for (int j = 0; j < 4; j++) { acc_s[i][j] = zero; acc_l[i][j] = zero; }

#pragma unroll 1
  for (int j = 0; j < jl_max; ++j) {
    const unsigned short* At_l = Pg + ((size_t)(tb_l + j) << 14) + kg8;
    const unsigned short* At_s = Pg + ((size_t)(tb_s + j) << 14) + kg8;
    const bool son = (j < js_max);                 // block-uniform
    const int kbase = j * 128;
#pragma unroll 1
    for (int ks2 = 0; ks2 < 2; ks2++) {
      const int ko = ks2 * 64;
#pragma unroll
      for (int c = 0; c < 4; c++)
        async16(At_l + (size_t)(rbase + 8 * c) * 128 + ko, Asl1 + c * 512);
      if (son) {
#pragma unroll
        for (int c = 0; c < 4; c++)
          async16(At_s + (size_t)(rbase + 8 * c) * 128 + ko, Asl0 + c * 512);
      }
#pragma unroll
      for (int c = 0; c < 4; c++)
        async16(Bb + (size_t)c * 8 * SQ + kbase + ko, Bsl + c * 512);
      asm volatile("s_waitcnt vmcnt(0)" ::: "memory");
      __syncthreads();
#pragma unroll
      for (int ks = 0; ks < 2; ks++) {
        const int ax = am ^ (ks * 32), bx = bn ^ (ks * 32);
        s16x8 bfr[4];
#pragma unroll
        for (int u = 0; u < 4; u++) bfr[u] = *(const s16x8*)(Bs + bx + u * 1024);
        s16x8 afl[4];
#pragma unroll
        for (int u = 0; u < 4; u++) afl[u] = *(const s16x8*)(As1 + ax + u * 1024);
#pragma unroll
        for (int tm = 0; tm < 4; tm++)
#pragma unroll
          for (int tn = 0; tn < 4; tn++)
            acc_l[tm][tn] = __builtin_amdgcn_mfma_f32_16x16x32_bf16(afl[tm], bfr[tn], acc_l[tm][tn], 0, 0, 0);
        if (son) {
          s16x8 afs[4];
#pragma unroll
          for (int u = 0; u < 4; u++) afs[u] = *(const s16x8*)(As0 + ax + u * 1024);
#pragma unroll
          for (int tm = 0; tm < 4; tm++)
#pragma unroll
            for (int tn = 0; tn < 4; tn++)
              acc_s[tm][tn] = __builtin_amdgcn_mfma_f32_16x16x32_bf16(afs[tm], bfr[tn], acc_s[tm][tn], 0, 0, 0);
        }
      }
      __syncthreads();
    }
  }

  // epilogue: both halves
#pragma unroll
  for (int half = 0; half < 2; half++) {
    const int mt = half ? mt_l : mt_s;
#pragma unroll
    for (int tm = 0; tm < 4; tm++) {
      int grow = mt * 128 + wm * 64 + tm * 16 + quad * 4;
      float rl[4];
#pragma unroll
      for (int g = 0; g < 4; g++) rl[g] = 1.0f / lg[grow + g];
#pragma unroll
      for (int tn = 0; tn < 4; tn++) {
        int col = n0 + wn * 64 + tn * 16 + l15;
        f32x4 v = half ? acc_l[tm][tn] : acc_s[tm][tn];
#pragma unroll
        for (int g = 0; g < 4; g++) {
          float val = v[g] * rl[g];
          float part = __shfl_xor(val, 1);
          if (ev) {
            float2 st; st.x = val; st.y = part;
            *(float2*)(Og + (size_t)(grow + g) * DM + col) = st;
          }
        }
      }
    }
  }
}

extern "C" void kernel_launch(void* const* d_in, const int* in_sizes, int n_in,
                              void* d_out, int out_size, void* d_ws, size_t ws_size,
                              hipStream_t stream) {
  const float* x  = (const float*)d_in[0];
  const float* Wq = (const float*)d_in[1];
  const float* Wk = (const float*)d_in[2];
  const float* Wv = (const float*)d_in[3];
  float* out = (float*)d_out;

  // workspace layout (bf16 elems). QKV first; packed S (69.2 MB) overlays the
  // dead-after-proj xb+Wb region. Peak 169.9 MB <= proven ws floor (174.1 MB).
  unsigned short* Qb  = (unsigned short*)d_ws;
  unsigned short* xb  = Qb + 3 * XN;
  unsigned short* Wb  = xb + XN;
  unsigned short* Sb  = xb;                              // overlay
  float* lfull = (float*)(Sb + (size_t)NB * NTILES * STILE);

  (void)ws_size; (void)in_sizes; (void)n_in; (void)out_size;

  cvt_all<<<NCVT + 64, 256, 0, stream>>>(x, Wq, Wk, Wv, xb, Wb, lfull);

  proj_all<<<dim3(MT / 128, 24), 256, 0, stream>>>(xb, Wb, Qb);

  qk_gemm<<<NB * NTILES, 256, 0, stream>>>(Qb, Qb + XN, Sb, lfull);

  pv_pair<<<512, 256, 0, stream>>>(Sb, Qb + 2 * XN, lfull, out);
}

// Round 11
// 402.348 us; speedup vs baseline: 1.1186x; 1.0445x over previous
//
#include <hip/hip_runtime.h>
#include <math.h>

#define SQ 4096
#define DM 1024
#define NB 4
#define MT (NB*SQ)   // 16384 flattened rows
#define XN ((size_t)MT*DM)
#define NCVT 19456   // (XN + 3*DM*DM)/1024 convert blocks in cvt_all
#define NTILES 528   // causal 128x128 tiles per batch (packed S)
#define STILE 16384  // elems per packed S tile (128*128)

typedef __attribute__((ext_vector_type(4))) float f32x4;
typedef __attribute__((ext_vector_type(8))) short s16x8;

// qk super-tile tables: triangle of 32 rows -> 36 supers of 4x4 tiles (row-major
// tri order). Full super (MT2>NT2): 16 tiles; diagonal: 10. Prefix over sizes:
__device__ const unsigned short SUP_PRE[37] = {
  0,10, 26,36, 52,68,78, 94,110,126,136, 152,168,184,200,210,
  226,242,258,274,290,300, 316,332,348,364,380,396,406,
  422,438,454,470,486,502,518,528};
__device__ const unsigned char SUP_MT2[36] = {
  0,1,1,2,2,2,3,3,3,3,4,4,4,4,4,5,5,5,5,5,5,6,6,6,6,6,6,6,7,7,7,7,7,7,7,7};
__device__ const unsigned char SUP_NT2[36] = {
  0,0,1,0,1,2,0,1,2,3,0,1,2,3,4,0,1,2,3,4,5,0,1,2,3,4,5,6,0,1,2,3,4,5,6,7};
__device__ const unsigned char DIAG_DM[10] = {0,1,1,2,2,2,3,3,3,3};
__device__ const unsigned char DIAG_DN[10] = {0,0,1,0,1,2,0,1,2,3};

__device__ __forceinline__ unsigned short f2bf(float f) {
  union { float f; unsigned int u; } v; v.f = f;
  unsigned int u = v.u;
  u += 0x7fffu + ((u >> 16) & 1u);   // RNE
  return (unsigned short)(u >> 16);
}

__device__ __forceinline__ float bf2f(unsigned short u) {
  union { unsigned int i; float f; } v; v.i = ((unsigned int)u) << 16;
  return v.f;
}

__device__ __forceinline__ void async16(const void* g, void* l) {
  __builtin_amdgcn_global_load_lds(
      (const __attribute__((address_space(1))) unsigned int*)g,
      (__attribute__((address_space(3))) unsigned int*)l, 16, 0, 0);
}

// ---------------- fp32 -> bf16 convert (all 4 inputs) + zero row-sum accumulator ----
__global__ __launch_bounds__(256)
void cvt_all(const float* __restrict__ x, const float* __restrict__ Wq,
             const float* __restrict__ Wk, const float* __restrict__ Wv,
             unsigned short* __restrict__ xb, unsigned short* __restrict__ Wb,
             float* __restrict__ l) {
  if (blockIdx.x >= NCVT) {
    int r = (blockIdx.x - NCVT) * 256 + threadIdx.x;
    l[r] = 0.f;
    return;
  }
  size_t i = ((size_t)blockIdx.x * 256 + threadIdx.x) * 4;
  const float* src; unsigned short* dst;
  if (i < XN) { src = x + i; dst = xb + i; }
  else {
    size_t r = i - XN;
    int w = (int)(r >> 20);                 // DM*DM == 2^20
    size_t off = r & (((size_t)1 << 20) - 1);
    src = (w == 0 ? Wq : (w == 1 ? Wk : Wv)) + off;
    dst = Wb + r;
  }
  float4 f = *(const float4*)src;
  ushort4 o;
  o.x = f2bf(f.x); o.y = f2bf(f.y); o.z = f2bf(f.z); o.w = f2bf(f.w);
  *(ushort4*)dst = o;
}

// ---------------- shared m97-style 128x128xBK64 K-loop, hoisted addressing ----------------
// NOTE (r0-r9 ledger): 8-phase / 256^2 variants (132.5/127.0/153.5 us) all lose to
// this 128^2 body; pv at n=64 3-blocks/CU (r8: +33 us) loses to n=128 2-blocks/CU;
// pv shared-V merge (r9) neutral. Structure wants MAX blocks/CU; operand L2
// residency is what separates proj (at floor) from qk/pv.
template<int LDA, int LDB>
__device__ __forceinline__ void gemm_tile_body(
    const unsigned short* __restrict__ A, const unsigned short* __restrict__ B,
    unsigned short* As, unsigned short* Bs,
    int m0, int n0, int kext, f32x4 acc[4][4]) {
  const int tid = threadIdx.x, lane = tid & 63, wid = tid >> 6;
  const int quad = lane >> 4, l15 = lane & 15;
  const int wm = wid & 1, wn = wid >> 1;

  const int rbase = wid * 32 + (lane >> 3);
  const int kg8   = ((lane & 7) ^ (lane >> 3)) * 8;
  const unsigned short* Ab = A + (size_t)(m0 + rbase) * LDA + kg8;
  const unsigned short* Bb = B + (size_t)(n0 + rbase) * LDB + kg8;
  unsigned short* Asl = As + (wid * 256 + lane) * 8;
  unsigned short* Bsl = Bs + (wid * 256 + lane) * 8;
  const int xorq = (quad ^ (l15 & 7)) * 8;
  const int am = (wm * 64 + l15) * 64 + xorq;
  const int bn = (wn * 64 + l15) * 64 + xorq;

  for (int k0 = 0; k0 < kext; k0 += 64) {
#pragma unroll
    for (int c = 0; c < 4; c++) {
      async16(Ab + (size_t)c * 8 * LDA + k0, Asl + c * 512);
      async16(Bb + (size_t)c * 8 * LDB + k0, Bsl + c * 512);
    }
    asm volatile("s_waitcnt vmcnt(0)" ::: "memory");
    __syncthreads();
#pragma unroll
    for (int ks = 0; ks < 2; ks++) {
      const int ax = am ^ (ks * 32), bx = bn ^ (ks * 32);
      s16x8 af[4], bfr[4];
#pragma unroll
      for (int t = 0; t < 4; t++) {
        af[t]  = *(const s16x8*)(As + ax + t * 1024);
        bfr[t] = *(const s16x8*)(Bs + bx + t * 1024);
      }
#pragma unroll
      for (int tm = 0; tm < 4; tm++)
#pragma unroll
        for (int tn = 0; tn < 4; tn++)
          acc[tm][tn] = __builtin_amdgcn_mfma_f32_16x16x32_bf16(af[tm], bfr[tn], acc[tm][tn], 0, 0, 0);
    }
    __syncthreads();
  }
}

// ---------------- QKV projection, single dispatch: Q,K (rope) + V (direct-Vt) ----------
// grid (128, 24): by>>3 = mat; n0 = (by&7)*128. x-fastest: consecutive blocks share
// the W slab (L2-resident). Do NOT swizzle this grid (regressed FETCH 136->323 MB).
__global__ __launch_bounds__(256, 3)
void proj_all(const unsigned short* __restrict__ A,
              const unsigned short* __restrict__ Wb,
              unsigned short* __restrict__ QKV) {
  __shared__ unsigned short As[128 * 64];
  __shared__ unsigned short Bs[128 * 64];
  const int lane = threadIdx.x & 63, wid = threadIdx.x >> 6;
  const int quad = lane >> 4, l15 = lane & 15;
  const int wm = wid & 1, wn = wid >> 1;
  const int mat = blockIdx.y >> 3;                 // 0,1 -> rope; 2 -> V
  const int m0 = blockIdx.x * 128, n0 = (blockIdx.y & 7) * 128;

  f32x4 zero = {0.f, 0.f, 0.f, 0.f};
  f32x4 acc[4][4];
#pragma unroll
  for (int i = 0; i < 4; i++)
#pragma unroll
    for (int j = 0; j < 4; j++) acc[i][j] = zero;

  gemm_tile_body<DM, DM>(A, Wb + (size_t)mat * DM * DM, As, Bs, m0, n0, DM, acc);

  if (mat < 2) {
    unsigned short* C = QKV + (size_t)mat * XN;
    const bool ev = (lane & 1) == 0;
#pragma unroll
    for (int tm = 0; tm < 4; tm++) {
      int rowb = m0 + wm * 64 + tm * 16 + quad * 4;
#pragma unroll
      for (int tn = 0; tn < 4; tn++) {
        int col = n0 + wn * 64 + tn * 16 + l15;
        f32x4 v = acc[tm][tn];
        float invr = exp2f(-(float)(col & ~1) * (13.287712379549449f / 1024.0f)) * 0.15915494309f;
#pragma unroll
        for (int g = 0; g < 4; g++) {
          int row = rowb + g;
          float rev = (float)(row & (SQ - 1)) * invr;
          rev -= floorf(rev);
          float sn, cs;
          __sincosf(rev * 6.283185307179586f, &sn, &cs);
          float part = __shfl_xor(v[g], 1);
          float e = ev ? v[g] : part;
          float o = ev ? part : v[g];
          float re = e * cs - o * sn;
          float ro = e * sn + o * cs;
          if (ev) {
            unsigned int pk = (unsigned int)f2bf(re) | ((unsigned int)f2bf(ro) << 16);
            *(unsigned int*)(C + (size_t)row * DM + col) = pk;
          }
        }
      }
    }
  } else {
    unsigned short* Vt = QKV + (size_t)2 * XN;     // [b][d][s]
#pragma unroll
    for (int tm = 0; tm < 4; tm++) {
      int rowb = m0 + wm * 64 + tm * 16 + quad * 4;
      int b = rowb >> 12;
      int s = rowb & (SQ - 1);                     // 4 rows, same batch, s..s+3
#pragma unroll
      for (int tn = 0; tn < 4; tn++) {
        int col = n0 + wn * 64 + tn * 16 + l15;
        f32x4 v = acc[tm][tn];
        ushort4 o;
        o.x = f2bf(v[0]); o.y = f2bf(v[1]); o.z = f2bf(v[2]); o.w = f2bf(v[3]);
        *(ushort4*)(Vt + (size_t)b * DM * SQ + (size_t)col * SQ + s) = o;
      }
    }
  }
}

// ---------------- pass1: P' = exp(QK^T/32), causal, PACKED-tile bf16 out ----------
// 2112 blocks. Order: 4x4 SUPER-TILES of the triangle (36 supers/batch, row-major
// tri). The 16 blocks of a full super share 4 Q-tiles + 4 K-tiles = 2 MB (fits
// per-XCD L2; 16-fold reuse on BOTH operands); consecutive supers share the Q
// row-slab. XCD-chunk swizzle (2112 = 8 x 264, bijective) keeps each XCD's
// concurrent blocks inside contiguous supers. Packed-S address uses tri(mt)+nt
// (order-independent; pv untouched).
__global__ __launch_bounds__(256, 3)
void qk_gemm(const unsigned short* __restrict__ Q, const unsigned short* __restrict__ K,
             unsigned short* __restrict__ S, float* __restrict__ l) {
  __shared__ unsigned short As[128 * 64];
  __shared__ unsigned short Bs[128 * 64];
  const int lane = threadIdx.x & 63, wid = threadIdx.x >> 6;
  const int quad = lane >> 4, l15 = lane & 15;
  const int wm = wid & 1, wn = wid >> 1;

  const int logical = (blockIdx.x & 7) * 264 + (blockIdx.x >> 3);
  const int b = logical / NTILES;
  const int t = logical - b * NTILES;

  // super-tile decode (block-uniform scalar scan, <=36 iters)
  int s = 0;
  while (SUP_PRE[s + 1] <= t) ++s;
  const int idx = t - SUP_PRE[s];
  const int MT2 = SUP_MT2[s], NT2 = SUP_NT2[s];
  int dm, dn;
  if (MT2 == NT2) { dm = DIAG_DM[idx]; dn = DIAG_DN[idx]; }
  else            { dm = idx >> 2;     dn = idx & 3; }
  const int mt = MT2 * 4 + dm, nt = NT2 * 4 + dn;
  const int tpack = mt * (mt + 1) / 2 + nt;        // packed-S tile id (tri order)

  const unsigned short* Qg = Q + (size_t)b * SQ * DM;
  const unsigned short* Kg = K + (size_t)b * SQ * DM;
  unsigned short* Sg = S + (size_t)b * NTILES * STILE + ((size_t)tpack << 14);
  float* lrow = l + b * SQ;

  f32x4 zero = {0.f, 0.f, 0.f, 0.f};
  f32x4 acc[4][4];
#pragma unroll
  for (int i = 0; i < 4; i++)
#pragma unroll
    for (int j = 0; j < 4; j++) acc[i][j] = zero;

  gemm_tile_body<DM, DM>(Qg, Kg, As, Bs, mt * 128, nt * 128, DM, acc);

  const bool ev = (lane & 1) == 0;
#pragma unroll
  for (int tm = 0; tm < 4; tm++) {
    int lr = wm * 64 + tm * 16 + quad * 4;          // tile-local row
    int grow = mt * 128 + lr;
    float rsum[4] = {0.f, 0.f, 0.f, 0.f};
#pragma unroll
    for (int tn = 0; tn < 4; tn++) {
      int lc = wn * 64 + tn * 16 + l15;             // tile-local col
      int gcol = nt * 128 + lc;
      f32x4 v = acc[tm][tn];
#pragma unroll
      for (int g = 0; g < 4; g++) {
        float p = (gcol <= grow + g) ? __expf(v[g] * 0.03125f) : 0.f;
        rsum[g] += p;
        float part = __shfl_xor(p, 1);
        if (ev) {
          unsigned int pk = (unsigned int)f2bf(p) | ((unsigned int)f2bf(part) << 16);
          *(unsigned int*)(Sg + (size_t)(lr + g) * 128 + lc) = pk;
        }
      }
    }
#pragma unroll
    for (int g = 0; g < 4; g++) {
      float s2 = rsum[g];
#pragma unroll
      for (int o = 8; o >= 1; o >>= 1) s2 += __shfl_xor(s2, o);
      if (l15 == 0) atomicAdd(&lrow[grow + g], s2);
    }
  }
}

// ---------------- pass2: O = (P' @ V)/l, merged complementary pair, shared-V staging ----
// 512 blocks (2/CU), logical = ((b*16 + p)*8 + nt): block computes m-tiles mt=p AND
// mt=31-p at n-tile nt in ONE k-loop over j=0..(31-p): V tile j staged once, P tiles
// for both columns while j <= p. XCD swizzle: nt-siblings share P tiles in L2.
__global__ __launch_bounds__(256, 2)
void pv_pair(const unsigned short* __restrict__ P, const unsigned short* __restrict__ Vt,
             const float* __restrict__ l, float* __restrict__ O) {
  __shared__ unsigned short As0[128 * 64];   // short column (mt = p)
  __shared__ unsigned short As1[128 * 64];   // long column (mt = 31-p)
  __shared__ unsigned short Bs[128 * 64];
  const int lane = threadIdx.x & 63, wid = threadIdx.x >> 6;
  const int quad = lane >> 4, l15 = lane & 15;
  const int wm = wid & 1, wn = wid >> 1;

  const int logical = (blockIdx.x & 7) * 64 + (blockIdx.x >> 3);
  const int b = logical >> 7;                      // 128 logical ids per batch
  const int p = (logical >> 3) & 15;
  const int nt = logical & 7;

  const unsigned short* Pg = P + (size_t)b * NTILES * STILE;
  const unsigned short* Vg = Vt + (size_t)b * DM * SQ;
  const float* lg = l + b * SQ;
  float* Og = O + (size_t)b * SQ * DM;
  const int n0 = nt * 128;

  const int mt_s = p, mt_l = 31 - p;
  const int tb_s = mt_s * (mt_s + 1) / 2;
  const int tb_l = mt_l * (mt_l + 1) / 2;
  const int js_max = p + 1, jl_max = 32 - p;

  const int rbase = wid * 32 + (lane >> 3);
  const int kg8 = ((lane & 7) ^ (lane >> 3)) * 8;
  const unsigned short* Bb = Vg + (size_t)(n0 + rbase) * SQ + kg8;
  unsigned short* Asl0 = As0 + (wid * 256 + lane) * 8;
  unsigned short* Asl1 = As1 + (wid * 256 + lane) * 8;
  unsigned short* Bsl  = Bs  + (wid * 256 + lane) * 8;
  const int xorq = (quad ^ (l15 & 7)) * 8;
  const int am = (wm * 64 + l15) * 64 + xorq;
  const int bn = (wn * 64 + l15) * 64 + xorq;
  const bool ev = (lane & 1) == 0;

  f32x4 zero = {0.f, 0.f, 0.f, 0.f};
  f32x4 acc_s[4][4], acc_l[4][4];
#pragma unroll
  for (int i = 0; i < 4; i++)
#pragma unroll
    for (int j = 0; j < 4; j++) { acc_s[i][j] = zero; acc_l[i][j] = zero; }

#pragma unroll 1
  for (int j = 0; j < jl_max; ++j) {
    const unsigned short* At_l = Pg + ((size_t)(tb_l + j) << 14) + kg8;
    const unsigned short* At_s = Pg + ((size_t)(tb_s + j) << 14) + kg8;
    const bool son = (j < js_max);                 // block-uniform
    const int kbase = j * 128;
#pragma unroll 1
    for (int ks2 = 0; ks2 < 2; ks2++) {
      const int ko = ks2 * 64;
#pragma unroll
      for (int c = 0; c < 4; c++)
        async16(At_l + (size_t)(rbase + 8 * c) * 128 + ko, Asl1 + c * 512);
      if (son) {
#pragma unroll
        for (int c = 0; c < 4; c++)
          async16(At_s + (size_t)(rbase + 8 * c) * 128 + ko, Asl0 + c * 512);
      }
#pragma unroll
      for (int c = 0; c < 4; c++)
        async16(Bb + (size_t)c * 8 * SQ + kbase + ko, Bsl + c * 512);
      asm volatile("s_waitcnt vmcnt(0)" ::: "memory");
      __syncthreads();
#pragma unroll
      for (int ks = 0; ks < 2; ks++) {
        const int ax = am ^ (ks * 32), bx = bn ^ (ks * 32);
        s16x8 bfr[4];
#pragma unroll
        for (int u = 0; u < 4; u++) bfr[u] = *(const s16x8*)(Bs + bx + u * 1024);
        s16x8 afl[4];
#pragma unroll
        for (int u = 0; u < 4; u++) afl[u] = *(const s16x8*)(As1 + ax + u * 1024);
#pragma unroll
        for (int tm = 0; tm < 4; tm++)
#pragma unroll
          for (int tn = 0; tn < 4; tn++)
            acc_l[tm][tn] = __builtin_amdgcn_mfma_f32_16x16x32_bf16(afl[tm], bfr[tn], acc_l[tm][tn], 0, 0, 0);
        if (son) {
          s16x8 afs[4];
#pragma unroll
          for (int u = 0; u < 4; u++) afs[u] = *(const s16x8*)(As0 + ax + u * 1024);
#pragma unroll
          for (int tm = 0; tm < 4; tm++)
#pragma unroll
            for (int tn = 0; tn < 4; tn++)
              acc_s[tm][tn] = __builtin_amdgcn_mfma_f32_16x16x32_bf16(afs[tm], bfr[tn], acc_s[tm][tn], 0, 0, 0);
        }
      }
      __syncthreads();
    }
  }

  // epilogue: both halves
#pragma unroll
  for (int half = 0; half < 2; half++) {
    const int mt = half ? mt_l : mt_s;
#pragma unroll
    for (int tm = 0; tm < 4; tm++) {
      int grow = mt * 128 + wm * 64 + tm * 16 + quad * 4;
      float rl[4];
#pragma unroll
      for (int g = 0; g < 4; g++) rl[g] = 1.0f / lg[grow + g];
#pragma unroll
      for (int tn = 0; tn < 4; tn++) {
        int col = n0 + wn * 64 + tn * 16 + l15;
        f32x4 v = half ? acc_l[tm][tn] : acc_s[tm][tn];
#pragma unroll
        for (int g = 0; g < 4; g++) {
          float val = v[g] * rl[g];
          float part = __shfl_xor(val, 1);
          if (ev) {
            float2 st; st.x = val; st.y = part;
            *(float2*)(Og + (size_t)(grow + g) * DM + col) = st;
          }
        }
      }
    }
  }
}

extern "C" void kernel_launch(void* const* d_in, const int* in_sizes, int n_in,
                              void* d_out, int out_size, void* d_ws, size_t ws_size,
                              hipStream_t stream) {
  const float* x  = (const float*)d_in[0];
  const float* Wq = (const float*)d_in[1];
  const float* Wk = (const float*)d_in[2];
  const float* Wv = (const float*)d_in[3];
  float* out = (float*)d_out;

  // workspace layout (bf16 elems). QKV first; packed S (69.2 MB) overlays the
  // dead-after-proj xb+Wb region. Peak 169.9 MB <= proven ws floor (174.1 MB).
  unsigned short* Qb  = (unsigned short*)d_ws;
  unsigned short* xb  = Qb + 3 * XN;
  unsigned short* Wb  = xb + XN;
  unsigned short* Sb  = xb;                              // overlay
  float* lfull = (float*)(Sb + (size_t)NB * NTILES * STILE);

  (void)ws_size; (void)in_sizes; (void)n_in; (void)out_size;

  cvt_all<<<NCVT + 64, 256, 0, stream>>>(x, Wq, Wk, Wv, xb, Wb, lfull);

  proj_all<<<dim3(MT / 128, 24), 256, 0, stream>>>(xb, Wb, Qb);

  qk_gemm<<<NB * NTILES, 256, 0, stream>>>(Qb, Qb + XN, Sb, lfull);

  pv_pair<<<512, 256, 0, stream>>>(Sb, Qb + 2 * XN, lfull, out);
}